// Round 11
// baseline (179.561 us; speedup 1.0000x reference)
//
#include <hip/hip_runtime.h>
#include <math.h>

#define G 64
#define NDIM 512
#define FIN 7
#define HID 64
#define CLS 2
#define KPOOL 128

typedef unsigned long long u64;

__device__ __forceinline__ float wred64(float v){
  #pragma unroll
  for (int o = 32; o > 0; o >>= 1) v += __shfl_xor(v, o, 64);
  return v;
}

// XCD-aware decode for 512-block per-graph-chunk kernels
#define XCD_DECODE(bid, g, chunk) \
  const int g = ((bid) & 7) + 8 * (((bid) >> 3) & 7); \
  const int chunk = (bid) >> 6;

// ---- build transposed bitmasks + degree: maskT[g][u][i], degf = rowsum ----
__global__ __launch_bounds__(256) void mask_kernel(const float* __restrict__ adj,
                                                   u64* __restrict__ maskT,
                                                   float* __restrict__ degf){
  const int wid = threadIdx.x >> 6, lane = threadIdx.x & 63;
  const int row = blockIdx.x * 4 + wid;          // [0, G*NDIM)
  const int g = row >> 9, i = row & 511;
  const float* ar = adj + (size_t)row * NDIM;
  u64 b[8];
  int dg = 0;
  #pragma unroll
  for (int u = 0; u < 8; u++){
    b[u] = __ballot(ar[u * 64 + lane] != 0.0f);
    dg += (int)__popcll(b[u]);
  }
  if (lane == 0){
    u64* mt = maskT + (size_t)g * 8 * NDIM + i;
    #pragma unroll
    for (int u = 0; u < 8; u++) mt[(size_t)u * NDIM] = b[u];
    degf[row] = (float)dg;
  }
}

// ---- A2 = adj@adj via popcount, register-tiled (4 rows in VGPRs) ----------
__global__ __launch_bounds__(256) void a2_kernel(const u64* __restrict__ maskT,
                                                 unsigned char* __restrict__ A2u8){
  const int bid = blockIdx.x;
  XCD_DECODE(bid, g, chunk)
  const int tid = threadIdx.x, wid = tid >> 6, lane = tid & 63;
  __shared__ u64 mt[8][NDIM];                    // 32 KB: whole graph's masks
  {
    const uint4* s4 = (const uint4*)(maskT + (size_t)g * 8 * NDIM);
    uint4* d4 = (uint4*)&mt[0][0];
    #pragma unroll
    for (int s = 0; s < 8; s++) d4[tid + 256 * s] = s4[tid + 256 * s];
  }
  __syncthreads();
  unsigned char* og = A2u8 + (size_t)g * NDIM * NDIM;
  #pragma unroll 1
  for (int rt = 0; rt < 4; rt++){
    const int ib = chunk * 64 + wid * 16 + rt * 4;
    u64 rm0[8], rm1[8], rm2[8], rm3[8];
    #pragma unroll
    for (int u = 0; u < 8; u++){                 // wave-uniform -> broadcast
      rm0[u] = mt[u][ib];  rm1[u] = mt[u][ib + 1];
      rm2[u] = mt[u][ib + 2]; rm3[u] = mt[u][ib + 3];
    }
    #pragma unroll
    for (int q = 0; q < 8; q++){
      int c0 = 0, c1 = 0, c2 = 0, c3 = 0;
      #pragma unroll
      for (int u = 0; u < 8; u++){
        u64 cm = mt[u][q * 64 + lane];           // per-lane, 2-way (free)
        c0 += (int)__popcll(cm & rm0[u]);
        c1 += (int)__popcll(cm & rm1[u]);
        c2 += (int)__popcll(cm & rm2[u]);
        c3 += (int)__popcll(cm & rm3[u]);
      }
      const int cc = q * 64 + lane;
      og[(size_t)(ib + 0) * NDIM + cc] = (unsigned char)c0;
      og[(size_t)(ib + 1) * NDIM + cc] = (unsigned char)c1;
      og[(size_t)(ib + 2) * NDIM + cc] = (unsigned char)c2;
      og[(size_t)(ib + 3) * NDIM + cc] = (unsigned char)c3;
    }
  }
}

// ---- d2 = A . degf ---------------------------------------------------------
__global__ __launch_bounds__(64) void d2_kernel(const u64* __restrict__ maskT,
                                                const float* __restrict__ degf,
                                                float* __restrict__ d2v){
  const int bid = blockIdx.x;
  XCD_DECODE(bid, g, chunk)
  const int i = chunk * 64 + threadIdx.x;
  u64 mi[8];
  #pragma unroll
  for (int u = 0; u < 8; u++) mi[u] = maskT[(size_t)g * 8 * NDIM + (size_t)u * NDIM + i];
  const float* s = degf + g * NDIM;
  float a = 0.f;
  #pragma unroll
  for (int u = 0; u < 8; u++){
    u64 mm = mi[u];
    while (mm){ int l = __builtin_ctzll(mm); mm &= mm - 1; a += s[u * 64 + l]; }
  }
  d2v[g * NDIM + i] = a;
}

// ---- d3 = A . d2 ; dvec = rsqrt(max(rowsum(M),1)) ; z = [d, d*x] ----------
__global__ __launch_bounds__(64) void d3_kernel(const u64* __restrict__ maskT,
                                                const float* __restrict__ degf,
                                                const float* __restrict__ d2v,
                                                const float* __restrict__ x,
                                                const float* __restrict__ panw,
                                                float* __restrict__ dvec,
                                                float* __restrict__ zbuf){
  const int bid = blockIdx.x;
  XCD_DECODE(bid, g, chunk)
  const int i = chunk * 64 + threadIdx.x;
  const int row = g * NDIM + i;
  u64 mi[8];
  #pragma unroll
  for (int u = 0; u < 8; u++) mi[u] = maskT[(size_t)g * 8 * NDIM + (size_t)u * NDIM + i];
  const float* s = d2v + g * NDIM;
  float d3 = 0.f;
  #pragma unroll
  for (int u = 0; u < 8; u++){
    u64 mm = mi[u];
    while (mm){ int l = __builtin_ctzll(mm); mm &= mm - 1; d3 += s[u * 64 + l]; }
  }
  const float d1 = degf[row], d2 = d2v[row];
  const float w0 = panw[0], ww1 = panw[1], ww2 = panw[2], ww3 = panw[3];
  const float c0 = w0, c1 = c0 * ww1, c2 = c1 * ww2, c3 = c2 * ww3;
  const float rs = c0 + c1 * d1 + c2 * d2 + c3 * d3;
  const float dd = rsqrtf(fmaxf(rs, 1.0f));
  dvec[row] = dd;
  float z[8];
  z[0] = dd;
  #pragma unroll
  for (int f = 0; f < FIN; f++) z[f + 1] = dd * x[(size_t)row * FIN + f];
  float4* zp = (float4*)(zbuf + (size_t)row * 8);
  zp[0] = make_float4(z[0], z[1], z[2], z[3]);
  zp[1] = make_float4(z[4], z[5], z[6], z[7]);
}

// ---- generic 8-wide neighbor-sum: Dst[i][e] = sum_{k in N(i)} Src[k][e] ---
__global__ __launch_bounds__(64) void w_kernel(const u64* __restrict__ maskT,
                                               const float* __restrict__ Src8,
                                               float* __restrict__ Dst8){
  const int bid = blockIdx.x;
  XCD_DECODE(bid, g, chunk)
  const int i = chunk * 64 + threadIdx.x;
  const int row = g * NDIM + i;
  u64 mi[8];
  #pragma unroll
  for (int u = 0; u < 8; u++) mi[u] = maskT[(size_t)g * 8 * NDIM + (size_t)u * NDIM + i];
  const float* s = Src8 + (size_t)g * NDIM * 8;
  float a[8] = {0.f,0.f,0.f,0.f,0.f,0.f,0.f,0.f};
  #pragma unroll
  for (int u = 0; u < 8; u++){
    u64 mm = mi[u];
    while (mm){
      int l = __builtin_ctzll(mm); mm &= mm - 1;
      const float4* p = (const float4*)(s + (size_t)(u * 64 + l) * 8);
      float4 v0 = p[0], v1 = p[1];
      a[0] += v0.x; a[1] += v0.y; a[2] += v0.z; a[3] += v0.w;
      a[4] += v1.x; a[5] += v1.y; a[6] += v1.z; a[7] += v1.w;
    }
  }
  float4* dp = (float4*)(Dst8 + (size_t)row * 8);
  dp[0] = make_float4(a[0], a[1], a[2], a[3]);
  dp[1] = make_float4(a[4], a[5], a[6], a[7]);
}

// ---- per-graph finalize: y, h, s1, s2, score, rank-select, xp scatter -----
__global__ __launch_bounds__(512) void fin_kernel(
    const float* __restrict__ dvec, const float* __restrict__ x,
    const float* __restrict__ w1v, const float* __restrict__ w2v,
    const float* __restrict__ w3v, const float* __restrict__ panw,
    const float* __restrict__ w1, const float* __restrict__ b1,
    const float* __restrict__ pvec, const float* __restrict__ beta,
    int* __restrict__ idxOut, float* __restrict__ valOut,
    float* __restrict__ xp)
{
  const int g = blockIdx.x, t = threadIdx.x;     // 512
  __shared__ float sv[NDIM];
  __shared__ float W1s[FIN * HID];
  __shared__ float ps[HID];
  if (t < FIN * HID) W1s[t] = w1[t];
  if (t < HID) ps[t] = pvec[t];
  const int row = g * NDIM + t;
  const float dd = dvec[row];
  const float4* p1 = (const float4*)(w1v + (size_t)row * 8);
  const float4* p2 = (const float4*)(w2v + (size_t)row * 8);
  const float4* p3 = (const float4*)(w3v + (size_t)row * 8);
  float4 a1lo = p1[0], a1hi = p1[1];
  float4 a2lo = p2[0], a2hi = p2[1];
  float4 a3lo = p3[0], a3hi = p3[1];
  float a1[8] = {a1lo.x,a1lo.y,a1lo.z,a1lo.w,a1hi.x,a1hi.y,a1hi.z,a1hi.w};
  float a2[8] = {a2lo.x,a2lo.y,a2lo.z,a2lo.w,a2hi.x,a2hi.y,a2hi.z,a2hi.w};
  float a3[8] = {a3lo.x,a3lo.y,a3lo.z,a3lo.w,a3hi.x,a3hi.y,a3hi.z,a3hi.w};
  const float w0 = panw[0], ww1 = panw[1], ww2 = panw[2], ww3 = panw[3];
  const float c0 = w0, c1 = c0 * ww1, c2 = c1 * ww2, c3 = c2 * ww3;
  const float e1 = a1[0], e2 = a2[0], e3 = a3[0];
  const float s2v = dd * (c0 * dd + c1 * e1 + c2 * e2 + c3 * e3);
  float yin[FIN];
  #pragma unroll
  for (int f = 0; f < FIN; f++){
    float zv = dd * x[(size_t)row * FIN + f];
    float y = c0 * zv;
    y += c1 * a1[f + 1];
    y += c2 * a2[f + 1];
    y += c3 * a3[f + 1];
    yin[f] = dd * y;
  }
  __syncthreads();                               // W1s/ps staged
  float hv[HID];
  float s1 = 0.f;
  #pragma unroll
  for (int o = 0; o < HID; o++){
    float zz = b1[o];
    #pragma unroll
    for (int f = 0; f < FIN; f++) zz = fmaf(yin[f], W1s[f * HID + o], zz);
    hv[o] = fmaxf(zz, 0.f);
    s1 = fmaf(hv[o], ps[o], s1);
  }
  const float sc = tanhf(beta[0] * s1 + beta[1] * s2v);
  sv[t] = sc;
  __syncthreads();
  int rank = 0;
  #pragma unroll 8
  for (int j = 0; j < NDIM; j++){
    float u_ = sv[j];
    rank += (u_ > sc || (u_ == sc && j < t)) ? 1 : 0;
  }
  if (rank < KPOOL){
    idxOut[g * KPOOL + rank] = t;
    valOut[g * KPOOL + rank] = sc;
    float* xr = xp + ((size_t)g * KPOOL + rank) * HID;
    #pragma unroll
    for (int o = 0; o < HID; o++) xr[o] = hv[o] * sc;
  }
}

// ---- pooled adjacency: Apool = Mn[idx,idx] + I, di (round-10 proven) ------
__global__ __launch_bounds__(512) void pool_kernel(
    const u64* __restrict__ maskT, const unsigned char* __restrict__ A2u8,
    const int* __restrict__ idx, const float* __restrict__ dvec,
    const float* __restrict__ panw,
    float* __restrict__ Apool, float* __restrict__ di)
{
  const int b = blockIdx.x;
  const int g = b >> 3, rowgrp = b & 7;
  const int tid = threadIdx.x, w = tid >> 6, lane = tid & 63;
  __shared__ int idxs[KPOOL];
  __shared__ float dp[KPOOL];
  __shared__ unsigned char arow[16][NDIM];       // 8 KB
  if (tid < KPOOL){
    int ia = idx[g * KPOOL + tid];
    idxs[tid] = ia;
    dp[tid] = dvec[g * NDIM + ia];
  }
  __syncthreads();
  const unsigned char* A2g = A2u8 + (size_t)g * NDIM * NDIM;
  #pragma unroll
  for (int e = 0; e < 2; e++){
    int j = w * 2 + e;
    int ir = idxs[rowgrp * 16 + j];
    *(uint2*)&arow[j][lane * 8] =
        *(const uint2*)(A2g + (size_t)ir * NDIM + lane * 8);
  }
  const int c0i = lane * 2, c1i = lane * 2 + 1;
  const int ic0 = idxs[c0i], ic1 = idxs[c1i];
  u64 cm0[8], cm1[8];
  {
    const u64* mg = maskT + (size_t)g * 8 * NDIM;
    #pragma unroll
    for (int u = 0; u < 8; u++){
      cm0[u] = mg[(size_t)u * NDIM + ic0];
      cm1[u] = mg[(size_t)u * NDIM + ic1];
    }
  }
  __syncthreads();
  const float w0 = panw[0], ww1 = panw[1], ww2 = panw[2], ww3 = panw[3];
  const float cc0 = w0, cc1 = cc0 * ww1, cc2 = cc1 * ww2, cc3 = cc2 * ww3;
  const float dc0 = dp[c0i], dc1 = dp[c1i];
  #pragma unroll
  for (int e = 0; e < 2; e++){
    const int j = w * 2 + e;
    const int r = rowgrp * 16 + j;
    const int ir = idxs[r];
    const float dpr = dp[r];
    const unsigned char* aj = arow[j];
    float a30 = 0.f, a31 = 0.f;
    #pragma unroll
    for (int u = 0; u < 8; u++){
      u64 m0 = cm0[u];
      while (m0){ int l = __builtin_ctzll(m0); m0 &= m0 - 1; a30 += (float)aj[u * 64 + l]; }
      u64 m1 = cm1[u];
      while (m1){ int l = __builtin_ctzll(m1); m1 &= m1 - 1; a31 += (float)aj[u * 64 + l]; }
    }
    float ab0 = (float)((cm0[ir >> 6] >> (ir & 63)) & 1ull);
    float ab1 = (float)((cm1[ir >> 6] >> (ir & 63)) & 1ull);
    float m0 = fmaf(cc3, a30, fmaf(cc2, (float)aj[ic0], cc1 * ab0));
    float m1 = fmaf(cc3, a31, fmaf(cc2, (float)aj[ic1], cc1 * ab1));
    if (r == c0i) m0 += cc0;
    if (r == c1i) m1 += cc0;
    float v0 = m0 * dpr * dc0;
    float v1 = m1 * dpr * dc1;
    if (r == c0i) v0 += 1.0f;
    if (r == c1i) v1 += 1.0f;
    float2 vv = make_float2(v0, v1);
    *(float2*)&Apool[((size_t)g * KPOOL + r) * KPOOL + c0i] = vv;
    float s = wred64(v0 + v1);
    if (lane == 0) di[g * KPOOL + r] = s > 0.f ? rsqrtf(s) : 0.f;
  }
}

// ---------------- pooled GCN: h2 = relu((An xp) W + b) ---------------------
__global__ __launch_bounds__(256) void gcn_kernel(
    const float* __restrict__ Apool, const float* __restrict__ di,
    const float* __restrict__ xp, const float* __restrict__ gw,
    const float* __restrict__ gb, float* __restrict__ h2)
{
  const int wid = threadIdx.x >> 6, lane = threadIdx.x & 63;
  const int row = blockIdx.x * 4 + wid;
  const int g = row >> 7, r = row & 127;
  const float dir = di[g * KPOOL + r];
  float acc = 0.f;
  for (int b = 0; b < KPOOL; b++){
    float an = Apool[(size_t)row * KPOOL + b] * dir * di[g * KPOOL + b];
    acc = fmaf(an, xp[((size_t)g * KPOOL + b) * HID + lane], acc);
  }
  __shared__ float ts[4][HID];
  ts[wid][lane] = acc;
  __syncthreads();
  float z = gb[lane];
  for (int f = 0; f < HID; f++) z = fmaf(ts[wid][f], gw[f * HID + lane], z);
  h2[(size_t)row * HID + lane] = fmaxf(z, 0.f);
}

// ---------------- head: pooled sum + linear + log_softmax ------------------
__global__ void head_kernel(const float* __restrict__ h2,
                            const float* __restrict__ lw,
                            const float* __restrict__ lb,
                            float* __restrict__ out)
{
  const int g = blockIdx.x;
  const int lane = threadIdx.x;
  float p = 0.f;
  for (int k = 0; k < KPOOL; k++) p += h2[((size_t)g * KPOOL + k) * HID + lane];
  float z0 = p * lw[lane * CLS + 0];
  float z1 = p * lw[lane * CLS + 1];
  z0 = wred64(z0);
  z1 = wred64(z1);
  if (lane == 0){
    float l0 = z0 + lb[0], l1 = z1 + lb[1];
    float m = fmaxf(l0, l1);
    float lse = m + logf(expf(l0 - m) + expf(l1 - m));
    out[g * CLS + 0] = l0 - lse;
    out[g * CLS + 1] = l1 - lse;
  }
}

extern "C" void kernel_launch(void* const* d_in, const int* in_sizes, int n_in,
                              void* d_out, int out_size, void* d_ws, size_t ws_size,
                              hipStream_t stream)
{
  const float* x    = (const float*)d_in[0];
  const float* adj  = (const float*)d_in[1];
  const float* panw = (const float*)d_in[2];
  const float* w1   = (const float*)d_in[3];
  const float* b1   = (const float*)d_in[4];
  const float* pvec = (const float*)d_in[5];
  const float* beta = (const float*)d_in[6];
  const float* gw   = (const float*)d_in[7];
  const float* gbv  = (const float*)d_in[8];
  const float* lw   = (const float*)d_in[9];
  const float* lb   = (const float*)d_in[10];
  float* out = (float*)d_out;

  char* ws = (char*)d_ws;
  const size_t NR = (size_t)G * NDIM;            // 32768 rows
  u64* maskT = (u64*)ws;                                    // 2 MB
  unsigned char* A2u8 = (unsigned char*)(ws + (1 << 21));   // 16.8 MB
  char* p = ws + (1 << 21) + 16777216;
  float* degf  = (float*)p;  p += NR * 4;
  float* d2v   = (float*)p;  p += NR * 4;
  float* dvec  = (float*)p;  p += NR * 4;
  float* zbuf  = (float*)p;  p += NR * 8 * 4;    // 1 MB
  float* w1v   = (float*)p;  p += NR * 8 * 4;
  float* w2v   = (float*)p;  p += NR * 8 * 4;
  float* w3v   = (float*)p;  p += NR * 8 * 4;
  int*   idx   = (int*)p;    p += (size_t)G * KPOOL * 4;
  float* vals  = (float*)p;  p += (size_t)G * KPOOL * 4;
  float* di    = (float*)p;  p += (size_t)G * KPOOL * 4;
  float* xp    = (float*)p;  p += (size_t)G * KPOOL * HID * 4;
  float* Apool = (float*)p;  p += (size_t)G * KPOOL * KPOOL * 4;
  float* h2    = (float*)p;

  mask_kernel<<<G * NDIM / 4, 256, 0, stream>>>(adj, maskT, degf);
  a2_kernel<<<512, 256, 0, stream>>>(maskT, A2u8);
  d2_kernel<<<512, 64, 0, stream>>>(maskT, degf, d2v);
  d3_kernel<<<512, 64, 0, stream>>>(maskT, degf, d2v, x, panw, dvec, zbuf);
  w_kernel<<<512, 64, 0, stream>>>(maskT, zbuf, w1v);
  w_kernel<<<512, 64, 0, stream>>>(maskT, w1v, w2v);
  w_kernel<<<512, 64, 0, stream>>>(maskT, w2v, w3v);
  fin_kernel<<<G, 512, 0, stream>>>(dvec, x, w1v, w2v, w3v, panw,
                                    w1, b1, pvec, beta, idx, vals, xp);
  pool_kernel<<<G * 8, 512, 0, stream>>>(maskT, A2u8, idx, dvec, panw, Apool, di);
  gcn_kernel<<<G * KPOOL / 4, 256, 0, stream>>>(Apool, di, xp, gw, gbv, h2);
  head_kernel<<<G, 64, 0, stream>>>(h2, lw, lb, out);
}

// Round 12
// 167.575 us; speedup vs baseline: 1.0715x; 1.0715x over previous
//
#include <hip/hip_runtime.h>
#include <math.h>

#define G 64
#define NDIM 512
#define FIN 7
#define HID 64
#define CLS 2
#define KPOOL 128

typedef unsigned long long u64;

__device__ __forceinline__ float wred64(float v){
  #pragma unroll
  for (int o = 32; o > 0; o >>= 1) v += __shfl_xor(v, o, 64);
  return v;
}

// XCD-aware decode for 512-block per-graph-chunk kernels
#define XCD_DECODE(bid, g, chunk) \
  const int g = ((bid) & 7) + 8 * (((bid) >> 3) & 7); \
  const int chunk = (bid) >> 6;

// ---- build transposed bitmasks + degree: maskT[g][u][i], degf = rowsum ----
__global__ __launch_bounds__(256) void mask_kernel(const float* __restrict__ adj,
                                                   u64* __restrict__ maskT,
                                                   float* __restrict__ degf){
  const int wid = threadIdx.x >> 6, lane = threadIdx.x & 63;
  const int row = blockIdx.x * 4 + wid;          // [0, G*NDIM)
  const int g = row >> 9, i = row & 511;
  const float* ar = adj + (size_t)row * NDIM;
  u64 b[8];
  int dg = 0;
  #pragma unroll
  for (int u = 0; u < 8; u++){
    b[u] = __ballot(ar[u * 64 + lane] != 0.0f);
    dg += (int)__popcll(b[u]);
  }
  if (lane == 0){
    u64* mt = maskT + (size_t)g * 8 * NDIM + i;
    #pragma unroll
    for (int u = 0; u < 8; u++) mt[(size_t)u * NDIM] = b[u];
    degf[row] = (float)dg;
  }
}

// ---- A2 rows for POOLED nodes only: A2p[g][r][c] = popc(m[idx_r] & m[c]) ---
__global__ __launch_bounds__(256) void a2p_kernel(const u64* __restrict__ maskT,
                                                  const int* __restrict__ idx,
                                                  unsigned char* __restrict__ A2p){
  const int bid = blockIdx.x;
  XCD_DECODE(bid, g, chunk)                      // chunk: pooled rows [16c,16c+16)
  const int tid = threadIdx.x, wid = tid >> 6, lane = tid & 63;
  __shared__ u64 mt[8][NDIM];                    // 32 KB: whole graph's masks
  __shared__ int idxs[16];
  {
    const uint4* s4 = (const uint4*)(maskT + (size_t)g * 8 * NDIM);
    uint4* d4 = (uint4*)&mt[0][0];
    #pragma unroll
    for (int s = 0; s < 8; s++) d4[tid + 256 * s] = s4[tid + 256 * s];
  }
  if (tid < 16) idxs[tid] = idx[g * KPOOL + chunk * 16 + tid];
  __syncthreads();
  unsigned char* og = A2p + ((size_t)g * KPOOL + chunk * 16) * NDIM;
  const int rbase = wid * 4;                     // 4 rows per wave
  const int i0 = idxs[rbase], i1 = idxs[rbase + 1];
  const int i2 = idxs[rbase + 2], i3 = idxs[rbase + 3];
  u64 rm0[8], rm1[8], rm2[8], rm3[8];
  #pragma unroll
  for (int u = 0; u < 8; u++){                   // wave-uniform -> broadcast
    rm0[u] = mt[u][i0]; rm1[u] = mt[u][i1];
    rm2[u] = mt[u][i2]; rm3[u] = mt[u][i3];
  }
  #pragma unroll
  for (int q = 0; q < 8; q++){
    int c0 = 0, c1 = 0, c2 = 0, c3 = 0;
    #pragma unroll
    for (int u = 0; u < 8; u++){
      u64 cm = mt[u][q * 64 + lane];             // per-lane, 2-way (free)
      c0 += (int)__popcll(cm & rm0[u]);
      c1 += (int)__popcll(cm & rm1[u]);
      c2 += (int)__popcll(cm & rm2[u]);
      c3 += (int)__popcll(cm & rm3[u]);
    }
    const int cc = q * 64 + lane;
    og[(size_t)(rbase + 0) * NDIM + cc] = (unsigned char)c0;
    og[(size_t)(rbase + 1) * NDIM + cc] = (unsigned char)c1;
    og[(size_t)(rbase + 2) * NDIM + cc] = (unsigned char)c2;
    og[(size_t)(rbase + 3) * NDIM + cc] = (unsigned char)c3;
  }
}

// ---- d2 = A . degf ---------------------------------------------------------
__global__ __launch_bounds__(64) void d2_kernel(const u64* __restrict__ maskT,
                                                const float* __restrict__ degf,
                                                float* __restrict__ d2v){
  const int bid = blockIdx.x;
  XCD_DECODE(bid, g, chunk)
  const int i = chunk * 64 + threadIdx.x;
  u64 mi[8];
  #pragma unroll
  for (int u = 0; u < 8; u++) mi[u] = maskT[(size_t)g * 8 * NDIM + (size_t)u * NDIM + i];
  const float* s = degf + g * NDIM;
  float a = 0.f;
  #pragma unroll
  for (int u = 0; u < 8; u++){
    u64 mm = mi[u];
    while (mm){ int l = __builtin_ctzll(mm); mm &= mm - 1; a += s[u * 64 + l]; }
  }
  d2v[g * NDIM + i] = a;
}

// ---- d3 = A . d2 ; dvec = rsqrt(max(rowsum(M),1)) ; z = [d, d*x] ----------
__global__ __launch_bounds__(64) void d3_kernel(const u64* __restrict__ maskT,
                                                const float* __restrict__ degf,
                                                const float* __restrict__ d2v,
                                                const float* __restrict__ x,
                                                const float* __restrict__ panw,
                                                float* __restrict__ dvec,
                                                float* __restrict__ zbuf){
  const int bid = blockIdx.x;
  XCD_DECODE(bid, g, chunk)
  const int i = chunk * 64 + threadIdx.x;
  const int row = g * NDIM + i;
  u64 mi[8];
  #pragma unroll
  for (int u = 0; u < 8; u++) mi[u] = maskT[(size_t)g * 8 * NDIM + (size_t)u * NDIM + i];
  const float* s = d2v + g * NDIM;
  float d3 = 0.f;
  #pragma unroll
  for (int u = 0; u < 8; u++){
    u64 mm = mi[u];
    while (mm){ int l = __builtin_ctzll(mm); mm &= mm - 1; d3 += s[u * 64 + l]; }
  }
  const float d1 = degf[row], d2 = d2v[row];
  const float w0 = panw[0], ww1 = panw[1], ww2 = panw[2], ww3 = panw[3];
  const float c0 = w0, c1 = c0 * ww1, c2 = c1 * ww2, c3 = c2 * ww3;
  const float rs = c0 + c1 * d1 + c2 * d2 + c3 * d3;
  const float dd = rsqrtf(fmaxf(rs, 1.0f));
  dvec[row] = dd;
  float z[8];
  z[0] = dd;
  #pragma unroll
  for (int f = 0; f < FIN; f++) z[f + 1] = dd * x[(size_t)row * FIN + f];
  float4* zp = (float4*)(zbuf + (size_t)row * 8);
  zp[0] = make_float4(z[0], z[1], z[2], z[3]);
  zp[1] = make_float4(z[4], z[5], z[6], z[7]);
}

// ---- generic 8-wide neighbor-sum: Dst[i][e] = sum_{k in N(i)} Src[k][e] ---
__global__ __launch_bounds__(64) void w_kernel(const u64* __restrict__ maskT,
                                               const float* __restrict__ Src8,
                                               float* __restrict__ Dst8){
  const int bid = blockIdx.x;
  XCD_DECODE(bid, g, chunk)
  const int i = chunk * 64 + threadIdx.x;
  const int row = g * NDIM + i;
  u64 mi[8];
  #pragma unroll
  for (int u = 0; u < 8; u++) mi[u] = maskT[(size_t)g * 8 * NDIM + (size_t)u * NDIM + i];
  const float* s = Src8 + (size_t)g * NDIM * 8;
  float a[8] = {0.f,0.f,0.f,0.f,0.f,0.f,0.f,0.f};
  #pragma unroll
  for (int u = 0; u < 8; u++){
    u64 mm = mi[u];
    while (mm){
      int l = __builtin_ctzll(mm); mm &= mm - 1;
      const float4* p = (const float4*)(s + (size_t)(u * 64 + l) * 8);
      float4 v0 = p[0], v1 = p[1];
      a[0] += v0.x; a[1] += v0.y; a[2] += v0.z; a[3] += v0.w;
      a[4] += v1.x; a[5] += v1.y; a[6] += v1.z; a[7] += v1.w;
    }
  }
  float4* dp = (float4*)(Dst8 + (size_t)row * 8);
  dp[0] = make_float4(a[0], a[1], a[2], a[3]);
  dp[1] = make_float4(a[4], a[5], a[6], a[7]);
}

// ---- per-graph finalize: y, h, s1, s2, score, rank-select, xp scatter -----
__global__ __launch_bounds__(512) void fin_kernel(
    const float* __restrict__ dvec, const float* __restrict__ x,
    const float* __restrict__ w1v, const float* __restrict__ w2v,
    const float* __restrict__ w3v, const float* __restrict__ panw,
    const float* __restrict__ w1, const float* __restrict__ b1,
    const float* __restrict__ pvec, const float* __restrict__ beta,
    int* __restrict__ idxOut, float* __restrict__ valOut,
    float* __restrict__ xp)
{
  const int g = blockIdx.x, t = threadIdx.x;     // 512
  __shared__ float sv[NDIM];
  __shared__ float W1s[FIN * HID];
  __shared__ float ps[HID];
  if (t < FIN * HID) W1s[t] = w1[t];
  if (t < HID) ps[t] = pvec[t];
  const int row = g * NDIM + t;
  const float dd = dvec[row];
  const float4* p1 = (const float4*)(w1v + (size_t)row * 8);
  const float4* p2 = (const float4*)(w2v + (size_t)row * 8);
  const float4* p3 = (const float4*)(w3v + (size_t)row * 8);
  float4 a1lo = p1[0], a1hi = p1[1];
  float4 a2lo = p2[0], a2hi = p2[1];
  float4 a3lo = p3[0], a3hi = p3[1];
  float a1[8] = {a1lo.x,a1lo.y,a1lo.z,a1lo.w,a1hi.x,a1hi.y,a1hi.z,a1hi.w};
  float a2[8] = {a2lo.x,a2lo.y,a2lo.z,a2lo.w,a2hi.x,a2hi.y,a2hi.z,a2hi.w};
  float a3[8] = {a3lo.x,a3lo.y,a3lo.z,a3lo.w,a3hi.x,a3hi.y,a3hi.z,a3hi.w};
  const float w0 = panw[0], ww1 = panw[1], ww2 = panw[2], ww3 = panw[3];
  const float c0 = w0, c1 = c0 * ww1, c2 = c1 * ww2, c3 = c2 * ww3;
  const float e1 = a1[0], e2 = a2[0], e3 = a3[0];
  const float s2v = dd * (c0 * dd + c1 * e1 + c2 * e2 + c3 * e3);
  float yin[FIN];
  #pragma unroll
  for (int f = 0; f < FIN; f++){
    float zv = dd * x[(size_t)row * FIN + f];
    float y = c0 * zv;
    y += c1 * a1[f + 1];
    y += c2 * a2[f + 1];
    y += c3 * a3[f + 1];
    yin[f] = dd * y;
  }
  __syncthreads();                               // W1s/ps staged
  float hv[HID];
  float s1 = 0.f;
  #pragma unroll
  for (int o = 0; o < HID; o++){
    float zz = b1[o];
    #pragma unroll
    for (int f = 0; f < FIN; f++) zz = fmaf(yin[f], W1s[f * HID + o], zz);
    hv[o] = fmaxf(zz, 0.f);
    s1 = fmaf(hv[o], ps[o], s1);
  }
  const float sc = tanhf(beta[0] * s1 + beta[1] * s2v);
  sv[t] = sc;
  __syncthreads();
  int rank = 0;
  #pragma unroll 8
  for (int j = 0; j < NDIM; j++){
    float u_ = sv[j];
    rank += (u_ > sc || (u_ == sc && j < t)) ? 1 : 0;
  }
  if (rank < KPOOL){
    idxOut[g * KPOOL + rank] = t;
    valOut[g * KPOOL + rank] = sc;
    float* xr = xp + ((size_t)g * KPOOL + rank) * HID;
    #pragma unroll
    for (int o = 0; o < HID; o++) xr[o] = hv[o] * sc;
  }
}

// ---- pooled adjacency: Apool = Mn[idx,idx] + I, di — A2p-row version ------
__global__ __launch_bounds__(512) void pool_kernel(
    const u64* __restrict__ maskT, const unsigned char* __restrict__ A2p,
    const int* __restrict__ idx, const float* __restrict__ dvec,
    const float* __restrict__ panw,
    float* __restrict__ Apool, float* __restrict__ di)
{
  const int b = blockIdx.x;
  const int g = b >> 3, rowgrp = b & 7;
  const int tid = threadIdx.x, w = tid >> 6, lane = tid & 63;
  __shared__ int idxs[KPOOL];
  __shared__ float dp[KPOOL];
  __shared__ unsigned char arow[16][NDIM];       // 8 KB
  if (tid < KPOOL){
    int ia = idx[g * KPOOL + tid];
    idxs[tid] = ia;
    dp[tid] = dvec[g * NDIM + ia];
  }
  __syncthreads();
  const unsigned char* A2pg = A2p + (size_t)g * KPOOL * NDIM;
  // stage the 16 pooled A2 rows of this rowgrp, coalesced
  #pragma unroll
  for (int e = 0; e < 2; e++){
    int j = w * 2 + e;
    int r = rowgrp * 16 + j;
    *(uint2*)&arow[j][lane * 8] =
        *(const uint2*)(A2pg + (size_t)r * NDIM + lane * 8);
  }
  const int c0i = lane * 2, c1i = lane * 2 + 1;
  const int ic0 = idxs[c0i], ic1 = idxs[c1i];
  u64 cm0[8], cm1[8];
  {
    const u64* mg = maskT + (size_t)g * 8 * NDIM;
    #pragma unroll
    for (int u = 0; u < 8; u++){
      cm0[u] = mg[(size_t)u * NDIM + ic0];
      cm1[u] = mg[(size_t)u * NDIM + ic1];
    }
  }
  __syncthreads();
  const float w0 = panw[0], ww1 = panw[1], ww2 = panw[2], ww3 = panw[3];
  const float cc0 = w0, cc1 = cc0 * ww1, cc2 = cc1 * ww2, cc3 = cc2 * ww3;
  const float dc0 = dp[c0i], dc1 = dp[c1i];
  #pragma unroll
  for (int e = 0; e < 2; e++){
    const int j = w * 2 + e;
    const int r = rowgrp * 16 + j;
    const int ir = idxs[r];
    const float dpr = dp[r];
    const unsigned char* aj = arow[j];
    float a30 = 0.f, a31 = 0.f;
    #pragma unroll
    for (int u = 0; u < 8; u++){
      u64 m0 = cm0[u];
      while (m0){ int l = __builtin_ctzll(m0); m0 &= m0 - 1; a30 += (float)aj[u * 64 + l]; }
      u64 m1 = cm1[u];
      while (m1){ int l = __builtin_ctzll(m1); m1 &= m1 - 1; a31 += (float)aj[u * 64 + l]; }
    }
    float ab0 = (float)((cm0[ir >> 6] >> (ir & 63)) & 1ull);
    float ab1 = (float)((cm1[ir >> 6] >> (ir & 63)) & 1ull);
    float m0 = fmaf(cc3, a30, fmaf(cc2, (float)aj[ic0], cc1 * ab0));
    float m1 = fmaf(cc3, a31, fmaf(cc2, (float)aj[ic1], cc1 * ab1));
    if (r == c0i) m0 += cc0;
    if (r == c1i) m1 += cc0;
    float v0 = m0 * dpr * dc0;
    float v1 = m1 * dpr * dc1;
    if (r == c0i) v0 += 1.0f;
    if (r == c1i) v1 += 1.0f;
    float2 vv = make_float2(v0, v1);
    *(float2*)&Apool[((size_t)g * KPOOL + r) * KPOOL + c0i] = vv;
    float s = wred64(v0 + v1);
    if (lane == 0) di[g * KPOOL + r] = s > 0.f ? rsqrtf(s) : 0.f;
  }
}

// ---------------- pooled GCN: h2 = relu((An xp) W + b) ---------------------
__global__ __launch_bounds__(256) void gcn_kernel(
    const float* __restrict__ Apool, const float* __restrict__ di,
    const float* __restrict__ xp, const float* __restrict__ gw,
    const float* __restrict__ gb, float* __restrict__ h2)
{
  const int wid = threadIdx.x >> 6, lane = threadIdx.x & 63;
  const int row = blockIdx.x * 4 + wid;
  const int g = row >> 7, r = row & 127;
  const float dir = di[g * KPOOL + r];
  float acc = 0.f;
  for (int b = 0; b < KPOOL; b++){
    float an = Apool[(size_t)row * KPOOL + b] * dir * di[g * KPOOL + b];
    acc = fmaf(an, xp[((size_t)g * KPOOL + b) * HID + lane], acc);
  }
  __shared__ float ts[4][HID];
  ts[wid][lane] = acc;
  __syncthreads();
  float z = gb[lane];
  for (int f = 0; f < HID; f++) z = fmaf(ts[wid][f], gw[f * HID + lane], z);
  h2[(size_t)row * HID + lane] = fmaxf(z, 0.f);
}

// ---------------- head: pooled sum + linear + log_softmax ------------------
__global__ void head_kernel(const float* __restrict__ h2,
                            const float* __restrict__ lw,
                            const float* __restrict__ lb,
                            float* __restrict__ out)
{
  const int g = blockIdx.x;
  const int lane = threadIdx.x;
  float p = 0.f;
  for (int k = 0; k < KPOOL; k++) p += h2[((size_t)g * KPOOL + k) * HID + lane];
  float z0 = p * lw[lane * CLS + 0];
  float z1 = p * lw[lane * CLS + 1];
  z0 = wred64(z0);
  z1 = wred64(z1);
  if (lane == 0){
    float l0 = z0 + lb[0], l1 = z1 + lb[1];
    float m = fmaxf(l0, l1);
    float lse = m + logf(expf(l0 - m) + expf(l1 - m));
    out[g * CLS + 0] = l0 - lse;
    out[g * CLS + 1] = l1 - lse;
  }
}

extern "C" void kernel_launch(void* const* d_in, const int* in_sizes, int n_in,
                              void* d_out, int out_size, void* d_ws, size_t ws_size,
                              hipStream_t stream)
{
  const float* x    = (const float*)d_in[0];
  const float* adj  = (const float*)d_in[1];
  const float* panw = (const float*)d_in[2];
  const float* w1   = (const float*)d_in[3];
  const float* b1   = (const float*)d_in[4];
  const float* pvec = (const float*)d_in[5];
  const float* beta = (const float*)d_in[6];
  const float* gw   = (const float*)d_in[7];
  const float* gbv  = (const float*)d_in[8];
  const float* lw   = (const float*)d_in[9];
  const float* lb   = (const float*)d_in[10];
  float* out = (float*)d_out;

  char* ws = (char*)d_ws;
  const size_t NR = (size_t)G * NDIM;            // 32768 rows
  u64* maskT = (u64*)ws;                                    // 2 MB
  unsigned char* A2p = (unsigned char*)(ws + (1 << 21));    // 4.2 MB (pooled rows)
  char* p = ws + (1 << 21) + (size_t)G * KPOOL * NDIM;
  float* degf  = (float*)p;  p += NR * 4;
  float* d2v   = (float*)p;  p += NR * 4;
  float* dvec  = (float*)p;  p += NR * 4;
  float* zbuf  = (float*)p;  p += NR * 8 * 4;    // 1 MB
  float* w1v   = (float*)p;  p += NR * 8 * 4;
  float* w2v   = (float*)p;  p += NR * 8 * 4;
  float* w3v   = (float*)p;  p += NR * 8 * 4;
  int*   idx   = (int*)p;    p += (size_t)G * KPOOL * 4;
  float* vals  = (float*)p;  p += (size_t)G * KPOOL * 4;
  float* di    = (float*)p;  p += (size_t)G * KPOOL * 4;
  float* xp    = (float*)p;  p += (size_t)G * KPOOL * HID * 4;
  float* Apool = (float*)p;  p += (size_t)G * KPOOL * KPOOL * 4;
  float* h2    = (float*)p;

  mask_kernel<<<G * NDIM / 4, 256, 0, stream>>>(adj, maskT, degf);
  d2_kernel<<<512, 64, 0, stream>>>(maskT, degf, d2v);
  d3_kernel<<<512, 64, 0, stream>>>(maskT, degf, d2v, x, panw, dvec, zbuf);
  w_kernel<<<512, 64, 0, stream>>>(maskT, zbuf, w1v);
  w_kernel<<<512, 64, 0, stream>>>(maskT, w1v, w2v);
  w_kernel<<<512, 64, 0, stream>>>(maskT, w2v, w3v);
  fin_kernel<<<G, 512, 0, stream>>>(dvec, x, w1v, w2v, w3v, panw,
                                    w1, b1, pvec, beta, idx, vals, xp);
  a2p_kernel<<<512, 256, 0, stream>>>(maskT, idx, A2p);
  pool_kernel<<<G * 8, 512, 0, stream>>>(maskT, A2p, idx, dvec, panw, Apool, di);
  gcn_kernel<<<G * KPOOL / 4, 256, 0, stream>>>(Apool, di, xp, gw, gbv, h2);
  head_kernel<<<G, 64, 0, stream>>>(h2, lw, lb, out);
}